// Round 7
// baseline (260.008 us; speedup 1.0000x reference)
//
#include <hip/hip_runtime.h>

// BSScanThru: out = brev8( (brev8(a) + brev8(b) + carry-chain) mod 256 ) & ~b
//
// Single-pass, zero inter-block communication, ONE barrier per block.
//
// Carry-lookahead identity: p_j = (c_j == 255) implies g_j = 0 (a wrapped
// byte sum cannot be exactly 255 while also wrapping). Therefore the carry
// into any position equals g of the NEAREST preceding element with c != 255.
// Each block computes its own carry-in by peeking backward from its tile
// base (wave 0: 64 coalesced elems per window, ballot c != 255, take g of
// the highest lane; step back on all-propagate, prob ~2^-512). Indices < 0
// act as {c=0,g=0} -> handles block 0 / array start with no special case.
// Peek is issued FIRST so its HBM latency overlaps the main tile loads.
//
// Block scan: per-wave __shfl_up carry-lookahead scan (register-only),
// 4 wave aggregates combined through LDS with a single __syncthreads.
//
// Output stored with nontemporal hint (native ext_vector_type — the HIP
// int4 struct is rejected by __builtin_nontemporal_store): keeps the
// 256 MB output stream out of L3 so input lines stay resident.
//
// Inputs: int32 (values 0..255). Output: int32.

#define BLK 256
#define EPT 16
#define TILE (BLK * EPT)   // 4096

typedef int iv4 __attribute__((ext_vector_type(4)));

// (g,p) packed: bit0 = g, bit1 = p. Identity: g=0,p=1 -> 2u.
__device__ __forceinline__ unsigned gp_combine(unsigned l, unsigned r) {
    unsigned g = (r & 1u) | ((r >> 1) & l & 1u);   // gr | (pr & gl)
    unsigned p = (l >> 1) & (r >> 1) & 1u;         // pl & pr
    return g | (p << 1);
}

__device__ __forceinline__ unsigned brev8(unsigned x) {
    return __brev(x) >> 24;
}

__global__ __launch_bounds__(BLK) void bss_onepass(const int* __restrict__ a,
                                                   const int* __restrict__ b,
                                                   int* __restrict__ out) {
    __shared__ unsigned sh_w[4];
    __shared__ unsigned s_cin;

    const int tid = threadIdx.x;
    const int lane = tid & 63;
    const int wid = tid >> 6;
    const long base0 = (long)blockIdx.x * TILE;
    const int base = (int)base0 + tid * EPT;

    // ---- block carry-in via backward peek (wave 0, issued FIRST) ----
    if (wid == 0) {
        unsigned cb = 0u;
        long w = base0 - 64;
        for (;;) {
            long idx = w + lane;
            unsigned cc = 0u, gg = 0u;   // idx < 0: virtual non-propagating, g=0
            if (idx >= 0) {
                unsigned s = brev8((unsigned)a[idx]) + brev8((unsigned)b[idx]);
                cc = s & 0xFFu;
                gg = s >> 8;
            }
            unsigned long long m = __ballot(cc != 0xFFu);
            if (m) {
                int hi = 63 - __clzll(m);        // nearest to tile base
                cb = (unsigned)__shfl((int)gg, hi, 64);
                break;
            }
            w -= 64;
        }
        if (lane == 0) s_cin = cb;
    }

    // ---- load 16 elems/thread ----
    iv4 av[4], bv[4];
#pragma unroll
    for (int q = 0; q < 4; ++q) {
        av[q] = *reinterpret_cast<const iv4*>(a + base + q * 4);
        bv[q] = *reinterpret_cast<const iv4*>(b + base + q * 4);
    }
    const int* ae = reinterpret_cast<const int*>(av);
    const int* be = reinterpret_cast<const int*>(bv);

    // ---- per-element wrapped sum + (g,p); thread-serial aggregate ----
    unsigned c[EPT], gp[EPT];
    unsigned tagg = 2u;  // identity
#pragma unroll
    for (int k = 0; k < EPT; ++k) {
        unsigned s = brev8((unsigned)ae[k]) + brev8((unsigned)be[k]);
        c[k] = s & 0xFFu;
        gp[k] = (s >> 8) | ((unsigned)(c[k] == 0xFFu) << 1);
        tagg = gp_combine(tagg, gp[k]);
    }

    // ---- per-wave inclusive shuffle scan (register-only) ----
    unsigned v = tagg;
#pragma unroll
    for (int off = 1; off < 64; off <<= 1) {
        unsigned u = (unsigned)__shfl_up((int)v, (unsigned)off, 64);
        if (lane >= off) v = gp_combine(u, v);
    }
    if (lane == 63) sh_w[wid] = v;
    __syncthreads();   // publishes sh_w AND s_cin

    // prefix over earlier waves (≤3 combines, LDS broadcast reads)
    unsigned pre = 2u;
#pragma unroll
    for (int w = 0; w < 3; ++w)
        if (w < wid) pre = gp_combine(pre, sh_w[w]);

    // thread-exclusive prefix within block
    unsigned exw = (unsigned)__shfl_up((int)v, 1u, 64);
    const unsigned ex = (lane == 0) ? pre : gp_combine(pre, exw);

    const unsigned cb = s_cin;

    // ---- resolve carries, final byte op, nontemporal store ----
    unsigned cin = (ex & 1u) | (((ex >> 1) & 1u) & cb);
    iv4 o[4];
    int* of = reinterpret_cast<int*>(o);
#pragma unroll
    for (int k = 0; k < EPT; ++k) {
        unsigned bev = (unsigned)be[k];
        unsigned res = (c[k] + cin) & 0xFFu;
        of[k] = (int)(brev8(res) & (~bev & 0xFFu));
        cin = (gp[k] & 1u) | (((gp[k] >> 1) & 1u) & cin);
    }
#pragma unroll
    for (int q = 0; q < 4; ++q)
        __builtin_nontemporal_store(o[q], reinterpret_cast<iv4*>(out + base + q * 4));
}

extern "C" void kernel_launch(void* const* d_in, const int* in_sizes, int n_in,
                              void* d_out, int out_size, void* d_ws, size_t ws_size,
                              hipStream_t stream) {
    const int* a = (const int*)d_in[0];
    const int* b = (const int*)d_in[1];
    int* out = (int*)d_out;
    const int n = in_sizes[0];      // 67108864
    const int nb = n / TILE;        // 16384

    bss_onepass<<<nb, BLK, 0, stream>>>(a, b, out);
}

// Round 8
// 186.565 us; speedup vs baseline: 1.3937x; 1.3937x over previous
//
#include <hip/hip_runtime.h>

// BSScanThru: out = brev8( (brev8(a) + brev8(b) + carry-chain) mod 256 ) & ~b
//
// Single-pass, zero inter-block communication, ONE barrier per block.
//
// Carry-lookahead identity: p_j = (c_j == 255) implies g_j = 0 (a wrapped
// byte sum cannot be exactly 255 while also wrapping). Therefore the carry
// into any position equals g of the NEAREST preceding element with c != 255.
// Each block computes its own carry-in by peeking backward from its tile
// base (wave 0: 64 coalesced elems per window, ballot c != 255, take g of
// the highest lane; step back on all-propagate, prob ~2^-512). Indices < 0
// act as {c=0,g=0} -> handles tile 0 / array start with no special case.
// Peek is issued FIRST so its latency overlaps the main tile loads.
//
// XCD-aware tile swizzle (bijective, nb % 8 == 0): consecutive tiles are
// processed by consecutive blocks on the SAME XCD, so the peek of tile t
// hits the local L2 (tile t-1's lines were just loaded there). Default
// round-robin dispatch would put t-1 on a different, non-coherent L2.
//
// Block scan: per-wave __shfl_up carry-lookahead scan (register-only),
// 4 wave aggregates combined through LDS with a single __syncthreads.
//
// Plain int4 stores (round-7 lesson: nontemporal stores bypass L2 write
// combining -> WRITE_SIZE +66%, dur 150->260 us. Reverted).
//
// Inputs: int32 (values 0..255). Output: int32.

#define BLK 256
#define EPT 16
#define TILE (BLK * EPT)   // 4096
#define NXCD 8

typedef int iv4 __attribute__((ext_vector_type(4)));

// (g,p) packed: bit0 = g, bit1 = p. Identity: g=0,p=1 -> 2u.
__device__ __forceinline__ unsigned gp_combine(unsigned l, unsigned r) {
    unsigned g = (r & 1u) | ((r >> 1) & l & 1u);   // gr | (pr & gl)
    unsigned p = (l >> 1) & (r >> 1) & 1u;         // pl & pr
    return g | (p << 1);
}

__device__ __forceinline__ unsigned brev8(unsigned x) {
    return __brev(x) >> 24;
}

__global__ __launch_bounds__(BLK, 8) void bss_onepass(const int* __restrict__ a,
                                                      const int* __restrict__ b,
                                                      int* __restrict__ out,
                                                      int nb) {
    __shared__ unsigned sh_w[4];
    __shared__ unsigned s_cin;

    const int tid = threadIdx.x;
    const int lane = tid & 63;
    const int wid = tid >> 6;

    // bijective XCD swizzle: XCD x gets contiguous tile range [x*nb/8, ...)
    const int bid = (int)blockIdx.x;
    const int tile = (bid & (NXCD - 1)) * (nb / NXCD) + (bid >> 3);

    const long base0 = (long)tile * TILE;
    const int base = (int)base0 + tid * EPT;

    // ---- block carry-in via backward peek (wave 0, issued FIRST) ----
    if (wid == 0) {
        unsigned cb = 0u;
        long w = base0 - 64;
        for (;;) {
            long idx = w + lane;
            unsigned cc = 0u, gg = 0u;   // idx < 0: virtual non-propagating, g=0
            if (idx >= 0) {
                unsigned s = brev8((unsigned)a[idx]) + brev8((unsigned)b[idx]);
                cc = s & 0xFFu;
                gg = s >> 8;
            }
            unsigned long long m = __ballot(cc != 0xFFu);
            if (m) {
                int hi = 63 - __clzll(m);        // nearest to tile base
                cb = (unsigned)__shfl((int)gg, hi, 64);
                break;
            }
            w -= 64;
        }
        if (lane == 0) s_cin = cb;
    }

    // ---- load 16 elems/thread ----
    iv4 av[4], bv[4];
#pragma unroll
    for (int q = 0; q < 4; ++q) {
        av[q] = *reinterpret_cast<const iv4*>(a + base + q * 4);
        bv[q] = *reinterpret_cast<const iv4*>(b + base + q * 4);
    }
    const int* ae = reinterpret_cast<const int*>(av);
    const int* be = reinterpret_cast<const int*>(bv);

    // ---- per-element wrapped sum + (g,p); thread-serial aggregate ----
    unsigned c[EPT], gp[EPT];
    unsigned tagg = 2u;  // identity
#pragma unroll
    for (int k = 0; k < EPT; ++k) {
        unsigned s = brev8((unsigned)ae[k]) + brev8((unsigned)be[k]);
        c[k] = s & 0xFFu;
        gp[k] = (s >> 8) | ((unsigned)(c[k] == 0xFFu) << 1);
        tagg = gp_combine(tagg, gp[k]);
    }

    // ---- per-wave inclusive shuffle scan (register-only) ----
    unsigned v = tagg;
#pragma unroll
    for (int off = 1; off < 64; off <<= 1) {
        unsigned u = (unsigned)__shfl_up((int)v, (unsigned)off, 64);
        if (lane >= off) v = gp_combine(u, v);
    }
    if (lane == 63) sh_w[wid] = v;
    __syncthreads();   // publishes sh_w AND s_cin

    // prefix over earlier waves (≤3 combines, LDS broadcast reads)
    unsigned pre = 2u;
#pragma unroll
    for (int w = 0; w < 3; ++w)
        if (w < wid) pre = gp_combine(pre, sh_w[w]);

    // thread-exclusive prefix within block
    unsigned exw = (unsigned)__shfl_up((int)v, 1u, 64);
    const unsigned ex = (lane == 0) ? pre : gp_combine(pre, exw);

    const unsigned cb = s_cin;

    // ---- resolve carries, final byte op, store ----
    unsigned cin = (ex & 1u) | (((ex >> 1) & 1u) & cb);
    iv4 o[4];
    int* of = reinterpret_cast<int*>(o);
#pragma unroll
    for (int k = 0; k < EPT; ++k) {
        unsigned bev = (unsigned)be[k];
        unsigned res = (c[k] + cin) & 0xFFu;
        of[k] = (int)(brev8(res) & (~bev & 0xFFu));
        cin = (gp[k] & 1u) | (((gp[k] >> 1) & 1u) & cin);
    }
#pragma unroll
    for (int q = 0; q < 4; ++q)
        *reinterpret_cast<iv4*>(out + base + q * 4) = o[q];
}

extern "C" void kernel_launch(void* const* d_in, const int* in_sizes, int n_in,
                              void* d_out, int out_size, void* d_ws, size_t ws_size,
                              hipStream_t stream) {
    const int* a = (const int*)d_in[0];
    const int* b = (const int*)d_in[1];
    int* out = (int*)d_out;
    const int n = in_sizes[0];      // 67108864
    const int nb = n / TILE;        // 16384 (divisible by 8)

    bss_onepass<<<nb, BLK, 0, stream>>>(a, b, out, nb);
}

// Round 9
// 155.676 us; speedup vs baseline: 1.6702x; 1.1984x over previous
//
#include <hip/hip_runtime.h>

// BSScanThru: out = brev8( (brev8(a) + brev8(b) + carry-chain) mod 256 ) & ~b
//
// Single-pass, zero inter-block communication, ONE barrier per block.
//
// Carry-lookahead identity: p_j = (c_j == 255) implies g_j = 0 (a wrapped
// byte sum cannot be exactly 255 while also wrapping). Therefore the carry
// into any position equals g of the NEAREST preceding element with c != 255.
// Each block computes its own carry-in by peeking backward from its tile
// base (wave 0: 64 coalesced elems per window, ballot c != 255, take g of
// the highest lane; step back on all-propagate, prob ~2^-512). Indices < 0
// act as {c=0,g=0} -> handles tile 0 / array start with no special case.
// Peek is issued FIRST so its latency overlaps the main tile loads.
//
// Carry propagation via the hardware adder (g,p disjoint => with A=G,
// B=G|P, the carry chain of A+B+cin IS the gp recurrence):
//   thread level: carry into elem k = bit k of  P ^ (G + (G|P) + cin)
//   wave level:   carry into lane  = bit lane of Pw ^ (Gw + (Gw|Pw) + cw)
//                 with Gw/Pw from two __ballot's (64-bit adds).
// This replaces the 16-step per-thread ripple and the 6-step __shfl_up
// scan with a couple of integer adds (round-5 -> round-9 change).
//
// No XCD swizzle (round-8 lesson: it broke natural L3 locality, FETCH
// +24%, WRITE +37%, dur 150->187 us). No nontemporal stores (round-7
// lesson: bypasses L2 write combining, WRITE +66%, dur 150->260 us).
//
// Inputs: int32 (values 0..255). Output: int32.

#define BLK 256
#define EPT 16
#define TILE (BLK * EPT)   // 4096

typedef int iv4 __attribute__((ext_vector_type(4)));

// (g,p) packed: bit0 = g, bit1 = p. Identity: g=0,p=1 -> 2u.
__device__ __forceinline__ unsigned gp_combine(unsigned l, unsigned r) {
    unsigned g = (r & 1u) | ((r >> 1) & l & 1u);   // gr | (pr & gl)
    unsigned p = (l >> 1) & (r >> 1) & 1u;         // pl & pr
    return g | (p << 1);
}

__device__ __forceinline__ unsigned brev8(unsigned x) {
    return __brev(x) >> 24;
}

__global__ __launch_bounds__(BLK) void bss_onepass(const int* __restrict__ a,
                                                   const int* __restrict__ b,
                                                   int* __restrict__ out) {
    __shared__ unsigned sh_w[4];
    __shared__ unsigned s_cin;

    const int tid = threadIdx.x;
    const int lane = tid & 63;
    const int wid = tid >> 6;
    const long base0 = (long)blockIdx.x * TILE;
    const int base = (int)base0 + tid * EPT;

    // ---- block carry-in via backward peek (wave 0, issued FIRST) ----
    if (wid == 0) {
        unsigned cb = 0u;
        long w = base0 - 64;
        for (;;) {
            long idx = w + lane;
            unsigned cc = 0u, gg = 0u;   // idx < 0: virtual non-propagating, g=0
            if (idx >= 0) {
                unsigned s = brev8((unsigned)a[idx]) + brev8((unsigned)b[idx]);
                cc = s & 0xFFu;
                gg = s >> 8;
            }
            unsigned long long m = __ballot(cc != 0xFFu);
            if (m) {
                int hi = 63 - __clzll(m);        // nearest to tile base
                cb = (unsigned)__shfl((int)gg, hi, 64);
                break;
            }
            w -= 64;
        }
        if (lane == 0) s_cin = cb;
    }

    // ---- load 16 elems/thread ----
    iv4 av[4], bv[4];
#pragma unroll
    for (int q = 0; q < 4; ++q) {
        av[q] = *reinterpret_cast<const iv4*>(a + base + q * 4);
        bv[q] = *reinterpret_cast<const iv4*>(b + base + q * 4);
    }
    const int* ae = reinterpret_cast<const int*>(av);
    const int* be = reinterpret_cast<const int*>(bv);

    // ---- per-element wrapped sum; build G (generate) / P (propagate) masks ----
    unsigned c[EPT];
    unsigned G = 0u, P = 0u;
#pragma unroll
    for (int k = 0; k < EPT; ++k) {
        unsigned s = brev8((unsigned)ae[k]) + brev8((unsigned)be[k]);
        c[k] = s & 0xFFu;
        G |= (s >> 8) << k;               // carry generated
        P |= ((c[k] + 1u) >> 8) << k;     // 1 iff c[k]==255
    }

    // ---- thread aggregate via adder trick (cin=0) ----
    const unsigned GoP = G | P;
    const unsigned g_t = (G + GoP) >> EPT;            // carry-out of 16 elems
    const unsigned p_t = (P == 0xFFFFu) ? 1u : 0u;

    // ---- wave-level masks (ballot) + wave aggregate ----
    const unsigned long long Gw = __ballot(g_t != 0u);
    const unsigned long long Pw = __ballot(p_t != 0u);
    if (lane == 63) {
        unsigned long long Tw = Gw + (Gw | Pw);
        unsigned g_w = (unsigned)(Tw < Gw);            // 64-bit carry-out
        unsigned p_w = (Pw == ~0ull) ? 1u : 0u;
        sh_w[wid] = g_w | (p_w << 1);
    }
    __syncthreads();   // publishes sh_w AND s_cin

    // carry into this wave: fold earlier-wave aggregates with block carry-in
    unsigned pre = 2u;
#pragma unroll
    for (int w = 0; w < 3; ++w)
        if (w < wid) pre = gp_combine(pre, sh_w[w]);
    const unsigned cb = s_cin;
    const unsigned cw = (pre & 1u) | (((pre >> 1) & 1u) & cb);

    // carry into this thread: bit `lane` of the 64-bit adder carry chain
    const unsigned long long Sw = Gw + (Gw | Pw) + (unsigned long long)cw;
    const unsigned c_t = (unsigned)(((Pw ^ Sw) >> lane) & 1ull);

    // carry into each element: bit k of the 16-bit adder carry chain
    const unsigned Cm = P ^ (G + GoP + c_t);

    // ---- final byte op, store ----
    iv4 o[4];
    int* of = reinterpret_cast<int*>(o);
#pragma unroll
    for (int k = 0; k < EPT; ++k) {
        unsigned res = (c[k] + ((Cm >> k) & 1u)) & 0xFFu;
        of[k] = (int)(brev8(res) & (~(unsigned)be[k] & 0xFFu));
    }
#pragma unroll
    for (int q = 0; q < 4; ++q)
        *reinterpret_cast<iv4*>(out + base + q * 4) = o[q];
}

extern "C" void kernel_launch(void* const* d_in, const int* in_sizes, int n_in,
                              void* d_out, int out_size, void* d_ws, size_t ws_size,
                              hipStream_t stream) {
    const int* a = (const int*)d_in[0];
    const int* b = (const int*)d_in[1];
    int* out = (int*)d_out;
    const int n = in_sizes[0];      // 67108864
    const int nb = n / TILE;        // 16384

    bss_onepass<<<nb, BLK, 0, stream>>>(a, b, out);
}